// Round 3
// baseline (10769.321 us; speedup 1.0000x reference)
//
#include <hip/hip_runtime.h>
#include <hip/hip_bf16.h>

#define TDIM 1024
#define HDIM 1024
#define IDIM 1024
#define BSZ  64

typedef __attribute__((ext_vector_type(4))) float  floatx4;
typedef __attribute__((ext_vector_type(2))) float  floatx2;
typedef __attribute__((ext_vector_type(8))) short  shortx8;

static __device__ __forceinline__ short f2bf(float x) {
    unsigned u = __builtin_bit_cast(unsigned, x);
    u += 0x7fffu + ((u >> 16) & 1u);           // round-to-nearest-even
    return (short)(u >> 16);
}

static __device__ __forceinline__ shortx8 pack8(floatx4 a, floatx4 b) {
    shortx8 r;
    r[0] = f2bf(a[0]); r[1] = f2bf(a[1]); r[2] = f2bf(a[2]); r[3] = f2bf(a[3]);
    r[4] = f2bf(b[0]); r[5] = f2bf(b[1]); r[6] = f2bf(b[2]); r[7] = f2bf(b[3]);
    return r;
}

// MALL-coherent 8B load, NO wait attached — caller must s_waitcnt before use.
static __device__ __forceinline__ unsigned long long ld_mall8(const unsigned* p) {
    unsigned long long v;
    asm volatile("global_load_dwordx2 %0, %1, off sc0 sc1"
                 : "=v"(v) : "v"(p) : "memory");
    return v;
}

// ---------------------------------------------------------------------------
// Phase A: out[m][n] = sum_k input[m][k] * W_ih[n][k] + b_ih[n] + b_hh[n]
// (unchanged — ~0.75 ms)
// ---------------------------------------------------------------------------
__global__ __launch_bounds__(256, 2)
void xp_gemm(const float* __restrict__ A, const float* __restrict__ W,
             const float* __restrict__ bih, const float* __restrict__ bhh,
             float* __restrict__ out)
{
    __shared__ short As[128 * 72];
    __shared__ short Bs[128 * 72];

    const int tid  = threadIdx.x;
    const int bx   = blockIdx.x;
    const int m0   = (bx >> 3) * 128;
    const int n0   = (bx & 7) * 128;
    const int lane = tid & 63;
    const int w    = tid >> 6;
    const int wm   = w & 1, wn = w >> 1;
    const int col  = lane & 15, quad = lane >> 4;

    const int srow = tid >> 1;
    const int scol = (tid & 1) * 32;
    const float* ap = A + (size_t)(m0 + srow) * IDIM + scol;
    const float* wp = W + (size_t)(n0 + srow) * IDIM + scol;
    short* asw = As + srow * 72 + scol;
    short* bsw = Bs + srow * 72 + scol;

    floatx4 acc[4][4];
#pragma unroll
    for (int i = 0; i < 4; i++)
#pragma unroll
        for (int j = 0; j < 4; j++) acc[i][j] = (floatx4){0.f, 0.f, 0.f, 0.f};

    for (int kt = 0; kt < IDIM; kt += 64) {
        floatx4 av[8], bv[8];
        const floatx4* pa = (const floatx4*)(ap + kt);
        const floatx4* pb = (const floatx4*)(wp + kt);
#pragma unroll
        for (int q = 0; q < 8; q++) { av[q] = pa[q]; bv[q] = pb[q]; }
        __syncthreads();
#pragma unroll
        for (int q = 0; q < 4; q++) {
            *(shortx8*)(asw + q * 8) = pack8(av[2 * q], av[2 * q + 1]);
            *(shortx8*)(bsw + q * 8) = pack8(bv[2 * q], bv[2 * q + 1]);
        }
        __syncthreads();
#pragma unroll
        for (int kb = 0; kb < 64; kb += 32) {
            shortx8 af[4], bf[4];
#pragma unroll
            for (int i = 0; i < 4; i++)
                af[i] = *(const shortx8*)(As + (wm * 64 + i * 16 + col) * 72 + kb + quad * 8);
#pragma unroll
            for (int j = 0; j < 4; j++)
                bf[j] = *(const shortx8*)(Bs + (wn * 64 + j * 16 + col) * 72 + kb + quad * 8);
#pragma unroll
            for (int i = 0; i < 4; i++)
#pragma unroll
                for (int j = 0; j < 4; j++)
                    acc[i][j] = __builtin_amdgcn_mfma_f32_16x16x32_bf16(af[i], bf[j], acc[i][j], 0, 0, 0);
        }
    }

#pragma unroll
    for (int j = 0; j < 4; j++) {
        const int n = n0 + wn * 64 + j * 16 + col;
        const float bias = bih[n] + bhh[n];
#pragma unroll
        for (int i = 0; i < 4; i++) {
            const int mb = m0 + wm * 64 + i * 16 + quad * 4;
#pragma unroll
            for (int r = 0; r < 4; r++)
                out[(size_t)(mb + r) * HDIM + n] = acc[i][j][r] + bias;
        }
    }
}

// ---------------------------------------------------------------------------
// Phase B: recurrence. 32 WGs of 512 threads = 4 batch-groups (gm, 16 batches)
// x 8 n-WGs (gn, 128 neurons; 8 waves x 16 neurons).  W_hh in registers.
//
// Sync design v3 — tag-in-word, zero acks, zero full drains:
//   - hbuf entry = uint [bf16(h) | tag = t].  One sc1 store publishes value
//     AND readiness atomically.  Producer never waits for store acks.
//   - consumer wave w polls its 4 KB slice (16 rows x 128 cols) until every
//     word's tag == t.  Stale tag -> retry.  A partially-completed load
//     still shows an old tag, so imprecise vmcnt is SAFE.
//   - poll loads for t+1 are issued BEFORE the epilogue stores; the validate
//     uses s_waitcnt vmcnt(8): oldest-first semantics waits the 16 loads,
//     leaves the 8 younger stores in flight.
//   - barriers are raw s_barrier + lgkmcnt(0) (LDS only) — no vmcnt drain,
//     so out[] nt-stores / prefetches / h-stores stay in flight across steps.
//   - depth-2 ping-pong safety: producer overwrites slot s (step t+1) only
//     after observing tags t+1 from all group members, which are issued only
//     after those members' slot-s loads returned.  MALL serializes per line.
// ---------------------------------------------------------------------------
__global__ __launch_bounds__(512, 1)
void rnn_rec(float* __restrict__ out,          // in: x_proj (fp32); overwritten with h
             const float* __restrict__ Whh, const float* __restrict__ h0,
             unsigned* __restrict__ hbuf)
{
    __shared__ short hlds[16 * 1032];   // 16 batches x 1024 k (bf16), pitch 1032

    const int tid  = threadIdx.x;
    const int gm   = blockIdx.x >> 3;   // 0..3
    const int gn   = blockIdx.x & 7;    // 0..7
    const int lane = tid & 63;
    const int w    = tid >> 6;          // 0..7
    const int col  = lane & 15, quad = lane >> 4;
    const int nglob = gn * 128 + w * 16 + col;

    // B-fragments: W_hh[n][k], k = kb*32 + quad*8 + j  (j = 0..7)
    shortx8 bfrag[32];
    {
        const float* wrow = Whh + (size_t)nglob * HDIM + quad * 8;
#pragma unroll
        for (int kb = 0; kb < 32; kb++) {
            const floatx4* p = (const floatx4*)(wrow + kb * 32);
            bfrag[kb] = pack8(p[0], p[1]);
        }
    }

    const int b0 = gm * 16 + quad * 4;
    // consumer slice: rows gm*16..+15, cols w*128 + lane*2 (+1), uint units
    const unsigned sbase = (unsigned)(gm * 16 * HDIM + w * 128 + lane * 2);
    const int ldsoff = w * 128 + lane * 2;      // shorts

    // prefetch x_proj for t = 0
    float xp[4], xpn[4];
#pragma unroll
    for (int r = 0; r < 4; r++)
        xp[r] = __builtin_nontemporal_load(out + (size_t)(b0 + r) * (TDIM * HDIM) + nglob);

    unsigned long long hv[16];

    for (int t = 0; t < TDIM; ++t) {
        // ================= staging =================
        if (t == 0) {
            // h0 is a plain kernel input — normal loads, convert, stage.
#pragma unroll
            for (int j = 0; j < 16; j++) {
                floatx2 f = *(const floatx2*)(h0 + (size_t)(gm * 16 + j) * HDIM + w * 128 + lane * 2);
                const unsigned pk = (unsigned)(unsigned short)f2bf(f[0]) |
                                    ((unsigned)(unsigned short)f2bf(f[1]) << 16);
                *(unsigned*)(hlds + j * 1032 + ldsoff) = pk;
            }
        } else {
            const unsigned long long tt  = (unsigned long long)(unsigned)t;
            const unsigned long long pat = (tt << 16) | (tt << 48);
            const unsigned* hsrc = hbuf + ((unsigned)(t & 1) << 16) + sbase;

            // hv was issued in the previous iteration's epilogue.
            asm volatile("s_waitcnt vmcnt(8)" ::: "memory");
            __builtin_amdgcn_sched_barrier(0);
            bool bad = false;
#pragma unroll
            for (int j = 0; j < 16; j++)
                bad |= ((hv[j] & 0xFFFF0000FFFF0000ULL) != pat);

            int guard = 0;
            while (__any(bad)) {
                if (++guard > 100000) break;      // hang fuse
#pragma unroll
                for (int j = 0; j < 16; j++)
                    hv[j] = ld_mall8(hsrc + (size_t)j * HDIM);
                asm volatile("s_waitcnt vmcnt(0)" ::: "memory");
                __builtin_amdgcn_sched_barrier(0);
                bad = false;
#pragma unroll
                for (int j = 0; j < 16; j++)
                    bad |= ((hv[j] & 0xFFFF0000FFFF0000ULL) != pat);
            }

            // extract bf16 halves -> LDS
#pragma unroll
            for (int j = 0; j < 16; j++) {
                const unsigned pk = (unsigned)(hv[j] & 0xFFFFu) |
                                    (((unsigned)(hv[j] >> 32) & 0xFFFFu) << 16);
                *(unsigned*)(hlds + j * 1032 + ldsoff) = pk;
            }
        }

        // prefetch next step's x_proj (consumed next iteration; never drained early)
        if (t + 1 < TDIM) {
#pragma unroll
            for (int r = 0; r < 4; r++)
                xpn[r] = __builtin_nontemporal_load(
                    out + (size_t)(b0 + r) * (TDIM * HDIM) + (size_t)(t + 1) * HDIM + nglob);
        }

        // bar1: all slices staged before MFMA.  LDS-only wait — no vmcnt drain.
        asm volatile("s_waitcnt lgkmcnt(0)" ::: "memory");
        __builtin_amdgcn_s_barrier();

        // ================= K loop: 32 MFMAs, 4 chains =================
        floatx4 a0 = (floatx4){0.f, 0.f, 0.f, 0.f};
        floatx4 a1 = a0, a2 = a0, a3 = a0;
#pragma unroll
        for (int kb = 0; kb < 32; kb += 4) {
            shortx8 f0 = *(const shortx8*)(hlds + col * 1032 + (kb + 0) * 32 + quad * 8);
            shortx8 f1 = *(const shortx8*)(hlds + col * 1032 + (kb + 1) * 32 + quad * 8);
            shortx8 f2 = *(const shortx8*)(hlds + col * 1032 + (kb + 2) * 32 + quad * 8);
            shortx8 f3 = *(const shortx8*)(hlds + col * 1032 + (kb + 3) * 32 + quad * 8);
            a0 = __builtin_amdgcn_mfma_f32_16x16x32_bf16(f0, bfrag[kb + 0], a0, 0, 0, 0);
            a1 = __builtin_amdgcn_mfma_f32_16x16x32_bf16(f1, bfrag[kb + 1], a1, 0, 0, 0);
            a2 = __builtin_amdgcn_mfma_f32_16x16x32_bf16(f2, bfrag[kb + 2], a2, 0, 0, 0);
            a3 = __builtin_amdgcn_mfma_f32_16x16x32_bf16(f3, bfrag[kb + 3], a3, 0, 0, 0);
        }
        floatx4 acc = (a0 + a1) + (a2 + a3);

        // ================= epilogue =================
        float hval[4];
#pragma unroll
        for (int r = 0; r < 4; r++)
            hval[r] = tanhf(xp[r] + acc[r]);

        // issue next-step poll loads FIRST (older than the stores below,
        // so vmcnt(8) at the next validate waits only these)
        if (t + 1 < TDIM) {
            const unsigned* nsrc = hbuf + ((unsigned)((t + 1) & 1) << 16) + sbase;
#pragma unroll
            for (int j = 0; j < 16; j++)
                hv[j] = ld_mall8(nsrc + (size_t)j * HDIM);
        }

        // publish h (tagged words, sc1, no ack wait)
        if (t + 1 < TDIM) {
            unsigned* hdst = hbuf + ((unsigned)((t + 1) & 1) << 16);
            const unsigned tagbits = (unsigned)(t + 1) << 16;
#pragma unroll
            for (int r = 0; r < 4; r++) {
                const unsigned pk = (unsigned)(unsigned short)f2bf(hval[r]) | tagbits;
                __hip_atomic_store(hdst + (size_t)(b0 + r) * HDIM + nglob, pk,
                                   __ATOMIC_RELAXED, __HIP_MEMORY_SCOPE_AGENT);
            }
        }

        // WG-private output writes (never drained on the critical path)
#pragma unroll
        for (int r = 0; r < 4; r++) {
            const int b = b0 + r;
            const size_t oidx = (size_t)b * (TDIM * HDIM) + (size_t)t * HDIM + nglob;
            __builtin_nontemporal_store(hval[r], out + oidx);
            if (t == TDIM - 1)
                out[(size_t)BSZ * TDIM * HDIM + (size_t)b * HDIM + nglob] = hval[r];
        }
        if (t + 1 < TDIM) {
#pragma unroll
            for (int r = 0; r < 4; r++) xp[r] = xpn[r];
        }

        // bar2: protect hlds from next staging.  LDS-only wait, no vmcnt drain.
        if (t + 1 < TDIM) {
            asm volatile("s_waitcnt lgkmcnt(0)" ::: "memory");
            __builtin_amdgcn_s_barrier();
        }
    }
}

// ---------------------------------------------------------------------------
extern "C" void kernel_launch(void* const* d_in, const int* in_sizes, int n_in,
                              void* d_out, int out_size, void* d_ws, size_t ws_size,
                              hipStream_t stream)
{
    const float* input = (const float*)d_in[0];
    const float* h0    = (const float*)d_in[1];
    const float* W_ih  = (const float*)d_in[2];
    const float* b_ih  = (const float*)d_in[3];
    const float* W_hh  = (const float*)d_in[4];
    const float* b_hh  = (const float*)d_in[5];
    float* out = (float*)d_out;

    unsigned* hbuf = (unsigned*)d_ws;   // 2 slots x 64 x 1024 tagged words = 512 KiB

    // tags from a previous run would alias this run's expectations — zero them.
    hipMemsetAsync(hbuf, 0, (size_t)2 * BSZ * HDIM * 4, stream);

    xp_gemm<<<dim3(4096), dim3(256), 0, stream>>>(input, W_ih, b_ih, b_hh, out);
    rnn_rec<<<dim3(32),   dim3(512), 0, stream>>>(out, W_hh, h0, hbuf);
}

// Round 6
// 4384.618 us; speedup vs baseline: 2.4562x; 2.4562x over previous
//
#include <hip/hip_runtime.h>
#include <hip/hip_bf16.h>

#define TDIM 1024
#define HDIM 1024
#define IDIM 1024
#define BSZ  64

typedef __attribute__((ext_vector_type(4))) float  floatx4;
typedef __attribute__((ext_vector_type(2))) float  floatx2;
typedef __attribute__((ext_vector_type(8))) short  shortx8;

static __device__ __forceinline__ short f2bf(float x) {
    unsigned u = __builtin_bit_cast(unsigned, x);
    u += 0x7fffu + ((u >> 16) & 1u);           // round-to-nearest-even
    return (short)(u >> 16);
}

static __device__ __forceinline__ shortx8 pack8(floatx4 a, floatx4 b) {
    shortx8 r;
    r[0] = f2bf(a[0]); r[1] = f2bf(a[1]); r[2] = f2bf(a[2]); r[3] = f2bf(a[3]);
    r[4] = f2bf(b[0]); r[5] = f2bf(b[1]); r[6] = f2bf(b[2]); r[7] = f2bf(b[3]);
    return r;
}

// ---- MALL-scope (agent-coherent) exchange primitives.  LESSON (round 4):
// sc0 = workgroup scope, sc1 = agent scope.  Cross-WG exchange MUST use sc1
// (MALL); workgroup-scope loads can legally hit stale per-CU L1 even within
// one XCD. ----
static __device__ __forceinline__ unsigned ld_flag(const unsigned* p) {
    unsigned v;
    asm volatile("global_load_dword %0, %1, off sc0 sc1" : "=v"(v) : "v"(p) : "memory");
    asm volatile("s_waitcnt vmcnt(0)" ::: "memory");
    return v;
}
static __device__ __forceinline__ unsigned ld_h(const unsigned* p) {
    unsigned v;
    asm volatile("global_load_dword %0, %1, off sc0 sc1" : "=v"(v) : "v"(p) : "memory");
    return v;
}
static __device__ __forceinline__ void st_h(unsigned short* p, unsigned short v) {
    asm volatile("global_store_short %0, %1, off sc0 sc1" :: "v"(p), "v"(v) : "memory");
}
static __device__ __forceinline__ void st_flag(unsigned* p, unsigned v) {
    asm volatile("global_store_dword %0, %1, off sc0 sc1" :: "v"(p), "v"(v) : "memory");
}

// ---------------------------------------------------------------------------
// Phase A: out[m][n] = sum_k input[m][k] * W_ih[n][k] + b_ih[n] + b_hh[n]
// (unchanged — ~0.75 ms)
// ---------------------------------------------------------------------------
__global__ __launch_bounds__(256, 2)
void xp_gemm(const float* __restrict__ A, const float* __restrict__ W,
             const float* __restrict__ bih, const float* __restrict__ bhh,
             float* __restrict__ out)
{
    __shared__ short As[128 * 72];
    __shared__ short Bs[128 * 72];

    const int tid  = threadIdx.x;
    const int bx   = blockIdx.x;
    const int m0   = (bx >> 3) * 128;
    const int n0   = (bx & 7) * 128;
    const int lane = tid & 63;
    const int w    = tid >> 6;
    const int wm   = w & 1, wn = w >> 1;
    const int col  = lane & 15, quad = lane >> 4;

    const int srow = tid >> 1;
    const int scol = (tid & 1) * 32;
    const float* ap = A + (size_t)(m0 + srow) * IDIM + scol;
    const float* wp = W + (size_t)(n0 + srow) * IDIM + scol;
    short* asw = As + srow * 72 + scol;
    short* bsw = Bs + srow * 72 + scol;

    floatx4 acc[4][4];
#pragma unroll
    for (int i = 0; i < 4; i++)
#pragma unroll
        for (int j = 0; j < 4; j++) acc[i][j] = (floatx4){0.f, 0.f, 0.f, 0.f};

    for (int kt = 0; kt < IDIM; kt += 64) {
        floatx4 av[8], bv[8];
        const floatx4* pa = (const floatx4*)(ap + kt);
        const floatx4* pb = (const floatx4*)(wp + kt);
#pragma unroll
        for (int q = 0; q < 8; q++) { av[q] = pa[q]; bv[q] = pb[q]; }
        __syncthreads();
#pragma unroll
        for (int q = 0; q < 4; q++) {
            *(shortx8*)(asw + q * 8) = pack8(av[2 * q], av[2 * q + 1]);
            *(shortx8*)(bsw + q * 8) = pack8(bv[2 * q], bv[2 * q + 1]);
        }
        __syncthreads();
#pragma unroll
        for (int kb = 0; kb < 64; kb += 32) {
            shortx8 af[4], bf[4];
#pragma unroll
            for (int i = 0; i < 4; i++)
                af[i] = *(const shortx8*)(As + (wm * 64 + i * 16 + col) * 72 + kb + quad * 8);
#pragma unroll
            for (int j = 0; j < 4; j++)
                bf[j] = *(const shortx8*)(Bs + (wn * 64 + j * 16 + col) * 72 + kb + quad * 8);
#pragma unroll
            for (int i = 0; i < 4; i++)
#pragma unroll
                for (int j = 0; j < 4; j++)
                    acc[i][j] = __builtin_amdgcn_mfma_f32_16x16x32_bf16(af[i], bf[j], acc[i][j], 0, 0, 0);
        }
    }

#pragma unroll
    for (int j = 0; j < 4; j++) {
        const int n = n0 + wn * 64 + j * 16 + col;
        const float bias = bih[n] + bhh[n];
#pragma unroll
        for (int i = 0; i < 4; i++) {
            const int mb = m0 + wm * 64 + i * 16 + quad * 4;
#pragma unroll
            for (int r = 0; r < 4; r++)
                out[(size_t)(mb + r) * HDIM + n] = acc[i][j][r] + bias;
        }
    }
}

// ---------------------------------------------------------------------------
// Phase B: recurrence.  64 WGs x 512 thr = 8 groups (g = bid>>3, 8 batches
// each) x 8 roles (role = bid&7, 128 neurons each).  W_hh in registers.
//
// Per-step protocol (all exchange at MALL / agent scope):
//   producer wave w': 4 h-stores (sc1) -> s_waitcnt vmcnt(0) -> lane0 sets
//     flag[g][role][w'] = t+1.  No intra-WG barrier on the release path.
//   consumer wave w: lanes poll the 8 flags {role=w, w'=0..7} until __all
//     >= t, then bulk-load its 8x128-col slice, stage to LDS.
//   barriers are raw s_barrier + lgkmcnt-only waits: out[] nt-stores and
//     x_proj prefetches are never force-drained on the hot path.
// Slot-overwrite safety (depth-2 ping-pong): WG p overwrites slot (t+1)&1 at
// epilogue t, after bar1(t) <= all 64 group flags >= t observed; each flag
// (q,w'') = t is stored after that wave's vmcnt(0), which retired its
// staging(t-1) loads of slot (t+1)&1.  Every reader finished first.
// Fail-fast fuse: 1<<16 poll iterations (~40 ms worst) — a protocol bug
// produces a bounded-time absmax failure, never a container-killing hang.
// ---------------------------------------------------------------------------
__global__ __launch_bounds__(512, 1)
void rnn_rec(float* __restrict__ out,          // in: x_proj (fp32); overwritten with h
             const float* __restrict__ Whh, const float* __restrict__ h0,
             unsigned short* __restrict__ hexch, unsigned* __restrict__ flags)
{
    __shared__ short hlds[16 * 1032];   // rows 0..7 = batches, 8..15 = zeros

    const int tid  = threadIdx.x;
    const int g    = blockIdx.x >> 3;   // 0..7  (batches g*8 .. g*8+7)
    const int role = blockIdx.x & 7;    // 0..7  (neurons role*128 .. +127)
    const int lane = tid & 63;
    const int w    = tid >> 6;          // 0..7
    const int col  = lane & 15, quad = lane >> 4;
    const int nglob = role * 128 + w * 16 + col;
    const int b0   = quad * 4;          // C rows; batches valid only b0 < 8

    // zero MFMA batch rows 8..15 once (A rows 8..15 = 0 -> C rows 8..15 = 0)
    {
        unsigned* z = (unsigned*)(hlds + 8 * 1032);
        for (int i = tid; i < 4 * 1032; i += 512) z[i] = 0u;
    }

    // B-fragments: W_hh[n][k], k = kb*32 + quad*8 + j
    shortx8 bfrag[32];
    {
        const float* wrow = Whh + (size_t)nglob * HDIM + quad * 8;
#pragma unroll
        for (int kb = 0; kb < 32; kb++) {
            const floatx4* p = (const floatx4*)(wrow + kb * 32);
            bfrag[kb] = pack8(p[0], p[1]);
        }
    }
    __syncthreads();                    // zeros visible before first MFMA

    const int bsafe = b0 & 7;           // in-range batch index for (dummy) loads
    float xp[4], xpn[4];
#pragma unroll
    for (int r = 0; r < 4; r++)
        xp[r] = __builtin_nontemporal_load(
            out + (size_t)(g * 8 + bsafe + r) * (TDIM * HDIM) + nglob);

    const int cc = w * 128 + lane * 2;  // this lane's exchange columns (k)
    // flags layout: flags[g*64 + role*8 + wave]
    const unsigned* fpoll = flags + (size_t)g * 64 + (size_t)w * 8;   // role=w slice
    unsigned*       fpub  = flags + (size_t)g * 64 + (size_t)role * 8 + w;

    for (int t = 0; t < TDIM; ++t) {
        // ================= staging =================
        if (t == 0) {
            const int c2 = tid * 2;     // 0..1022
#pragma unroll
            for (int j = 0; j < 8; j++) {
                floatx2 f = *(const floatx2*)(h0 + (size_t)(g * 8 + j) * HDIM + c2);
                const unsigned pk = (unsigned)(unsigned short)f2bf(f[0]) |
                                    ((unsigned)(unsigned short)f2bf(f[1]) << 16);
                *(unsigned*)(hlds + j * 1032 + c2) = pk;
            }
        } else {
            // poll the 8 producer-wave flags for role w (lane-parallel)
            int guard = 0;
            for (;;) {
                const unsigned f = ld_flag(fpoll + (lane & 7));
                if (__all((int)(f >= (unsigned)t))) break;
                if (++guard > (1 << 16)) break;      // FAIL-FAST fuse
                asm volatile("s_sleep 1");           // be nice to the MALL
            }
            // bulk-load slice: 8 batches x 2 cols per lane (volatile-asm ordered)
            const unsigned short* base =
                hexch + (size_t)(t & 1) * (8 * 8 * 1024) + (size_t)g * (8 * 1024) + cc;
            unsigned hv[8];
#pragma unroll
            for (int j = 0; j < 8; j++)
                hv[j] = ld_h((const unsigned*)(base + j * 1024));
            asm volatile("s_waitcnt vmcnt(0)" ::: "memory");
            __builtin_amdgcn_sched_barrier(0);
#pragma unroll
            for (int j = 0; j < 8; j++)
                *(unsigned*)(hlds + j * 1032 + cc) = hv[j];
        }

        // bar1: all slices staged (LDS-only wait, no vmcnt drain)
        asm volatile("s_waitcnt lgkmcnt(0)" ::: "memory");
        __builtin_amdgcn_s_barrier();

        // ================= K loop: 32 MFMAs, 4 chains =================
        floatx4 a0 = (floatx4){0.f, 0.f, 0.f, 0.f};
        floatx4 a1 = a0, a2 = a0, a3 = a0;
#pragma unroll
        for (int kb = 0; kb < 32; kb += 4) {
            shortx8 f0 = *(const shortx8*)(hlds + col * 1032 + (kb + 0) * 32 + quad * 8);
            shortx8 f1 = *(const shortx8*)(hlds + col * 1032 + (kb + 1) * 32 + quad * 8);
            shortx8 f2 = *(const shortx8*)(hlds + col * 1032 + (kb + 2) * 32 + quad * 8);
            shortx8 f3 = *(const shortx8*)(hlds + col * 1032 + (kb + 3) * 32 + quad * 8);
            a0 = __builtin_amdgcn_mfma_f32_16x16x32_bf16(f0, bfrag[kb + 0], a0, 0, 0, 0);
            a1 = __builtin_amdgcn_mfma_f32_16x16x32_bf16(f1, bfrag[kb + 1], a1, 0, 0, 0);
            a2 = __builtin_amdgcn_mfma_f32_16x16x32_bf16(f2, bfrag[kb + 2], a2, 0, 0, 0);
            a3 = __builtin_amdgcn_mfma_f32_16x16x32_bf16(f3, bfrag[kb + 3], a3, 0, 0, 0);
        }
        floatx4 acc = (a0 + a1) + (a2 + a3);

        // ================= epilogue =================
        float hval[4];
#pragma unroll
        for (int r = 0; r < 4; r++)
            hval[r] = tanhf(xp[r] + acc[r]);

        // release: h stores -> per-wave ack -> per-wave flag.
        if (t + 1 < TDIM) {
            if (b0 < 8) {
                unsigned short* hd =
                    hexch + (size_t)((t + 1) & 1) * (8 * 8 * 1024) + (size_t)g * (8 * 1024);
#pragma unroll
                for (int r = 0; r < 4; r++)
                    st_h(hd + (size_t)(b0 + r) * 1024 + nglob,
                         (unsigned short)f2bf(hval[r]));
            }
            asm volatile("s_waitcnt vmcnt(0)" ::: "memory");
            if (lane == 0) st_flag(fpub, (unsigned)(t + 1));
        }

        // off the release path: WG-private out[] writes + next x_proj prefetch
        if (b0 < 8) {
#pragma unroll
            for (int r = 0; r < 4; r++) {
                const int b = g * 8 + b0 + r;
                const size_t oidx = (size_t)b * (TDIM * HDIM) + (size_t)t * HDIM + nglob;
                __builtin_nontemporal_store(hval[r], out + oidx);
                if (t == TDIM - 1)
                    out[(size_t)BSZ * TDIM * HDIM + (size_t)b * HDIM + nglob] = hval[r];
            }
        }
        if (t + 1 < TDIM) {
#pragma unroll
            for (int r = 0; r < 4; r++)
                xpn[r] = __builtin_nontemporal_load(
                    out + (size_t)(g * 8 + bsafe + r) * (TDIM * HDIM) + (size_t)(t + 1) * HDIM + nglob);
#pragma unroll
            for (int r = 0; r < 4; r++) xp[r] = xpn[r];
        }

        // bar2: protect hlds from next staging (LDS-only wait)
        if (t + 1 < TDIM) {
            asm volatile("s_waitcnt lgkmcnt(0)" ::: "memory");
            __builtin_amdgcn_s_barrier();
        }
    }
}

// ---------------------------------------------------------------------------
extern "C" void kernel_launch(void* const* d_in, const int* in_sizes, int n_in,
                              void* d_out, int out_size, void* d_ws, size_t ws_size,
                              hipStream_t stream)
{
    const float* input = (const float*)d_in[0];
    const float* h0    = (const float*)d_in[1];
    const float* W_ih  = (const float*)d_in[2];
    const float* b_ih  = (const float*)d_in[3];
    const float* W_hh  = (const float*)d_in[4];
    const float* b_hh  = (const float*)d_in[5];
    float* out = (float*)d_out;

    char* ws = (char*)d_ws;
    unsigned*       flags = (unsigned*)ws;                 // 8 groups x 64 flags = 2 KiB
    unsigned short* hexch = (unsigned short*)(ws + 16384); // 2 x 8g x 8b x 1024 bf16 = 256 KiB

    hipMemsetAsync(ws, 0, 16384, stream);                  // flags

    xp_gemm<<<dim3(4096), dim3(256), 0, stream>>>(input, W_ih, b_ih, b_hh, out);
    rnn_rec<<<dim3(64),   dim3(512), 0, stream>>>(out, W_hh, h0, hexch, flags);
}

// Round 7
// 3864.803 us; speedup vs baseline: 2.7865x; 1.1345x over previous
//
#include <hip/hip_runtime.h>
#include <hip/hip_bf16.h>

#define TDIM 1024
#define HDIM 1024
#define IDIM 1024
#define BSZ  64

typedef __attribute__((ext_vector_type(4))) float  floatx4;
typedef __attribute__((ext_vector_type(2))) float  floatx2;
typedef __attribute__((ext_vector_type(8))) short  shortx8;

static __device__ __forceinline__ short f2bf(float x) {
    unsigned u = __builtin_bit_cast(unsigned, x);
    u += 0x7fffu + ((u >> 16) & 1u);           // round-to-nearest-even
    return (short)(u >> 16);
}

static __device__ __forceinline__ shortx8 pack8(floatx4 a, floatx4 b) {
    shortx8 r;
    r[0] = f2bf(a[0]); r[1] = f2bf(a[1]); r[2] = f2bf(a[2]); r[3] = f2bf(a[3]);
    r[4] = f2bf(b[0]); r[5] = f2bf(b[1]); r[6] = f2bf(b[2]); r[7] = f2bf(b[3]);
    return r;
}

// ---- MALL-scope (agent-coherent) primitives.  LESSON (round 4): sc0 alone
// is sub-agent scope; cross-WG exchange MUST use sc0+sc1 (MALL).  LESSON
// (round 6): vmcnt retires IN-ORDER — any poll using vmcnt(0) must run with
// an otherwise-empty VMEM queue, or it silently drains store-acks. ----
static __device__ __forceinline__ unsigned long long ld_mall8(const unsigned* p) {
    unsigned long long v;
    asm volatile("global_load_dwordx2 %0, %1, off sc0 sc1"
                 : "=v"(v) : "v"(p) : "memory");
    return v;
}
static __device__ __forceinline__ void st_tag(unsigned* p, unsigned v) {
    asm volatile("global_store_dword %0, %1, off sc0 sc1" :: "v"(p), "v"(v) : "memory");
}

// ---------------------------------------------------------------------------
// Phase A: out[m][n] = sum_k input[m][k] * W_ih[n][k] + b_ih[n] + b_hh[n]
// (unchanged — ~0.75 ms)
// ---------------------------------------------------------------------------
__global__ __launch_bounds__(256, 2)
void xp_gemm(const float* __restrict__ A, const float* __restrict__ W,
             const float* __restrict__ bih, const float* __restrict__ bhh,
             float* __restrict__ out)
{
    __shared__ short As[128 * 72];
    __shared__ short Bs[128 * 72];

    const int tid  = threadIdx.x;
    const int bx   = blockIdx.x;
    const int m0   = (bx >> 3) * 128;
    const int n0   = (bx & 7) * 128;
    const int lane = tid & 63;
    const int w    = tid >> 6;
    const int wm   = w & 1, wn = w >> 1;
    const int col  = lane & 15, quad = lane >> 4;

    const int srow = tid >> 1;
    const int scol = (tid & 1) * 32;
    const float* ap = A + (size_t)(m0 + srow) * IDIM + scol;
    const float* wp = W + (size_t)(n0 + srow) * IDIM + scol;
    short* asw = As + srow * 72 + scol;
    short* bsw = Bs + srow * 72 + scol;

    floatx4 acc[4][4];
#pragma unroll
    for (int i = 0; i < 4; i++)
#pragma unroll
        for (int j = 0; j < 4; j++) acc[i][j] = (floatx4){0.f, 0.f, 0.f, 0.f};

    for (int kt = 0; kt < IDIM; kt += 64) {
        floatx4 av[8], bv[8];
        const floatx4* pa = (const floatx4*)(ap + kt);
        const floatx4* pb = (const floatx4*)(wp + kt);
#pragma unroll
        for (int q = 0; q < 8; q++) { av[q] = pa[q]; bv[q] = pb[q]; }
        __syncthreads();
#pragma unroll
        for (int q = 0; q < 4; q++) {
            *(shortx8*)(asw + q * 8) = pack8(av[2 * q], av[2 * q + 1]);
            *(shortx8*)(bsw + q * 8) = pack8(bv[2 * q], bv[2 * q + 1]);
        }
        __syncthreads();
#pragma unroll
        for (int kb = 0; kb < 64; kb += 32) {
            shortx8 af[4], bf[4];
#pragma unroll
            for (int i = 0; i < 4; i++)
                af[i] = *(const shortx8*)(As + (wm * 64 + i * 16 + col) * 72 + kb + quad * 8);
#pragma unroll
            for (int j = 0; j < 4; j++)
                bf[j] = *(const shortx8*)(Bs + (wn * 64 + j * 16 + col) * 72 + kb + quad * 8);
#pragma unroll
            for (int i = 0; i < 4; i++)
#pragma unroll
                for (int j = 0; j < 4; j++)
                    acc[i][j] = __builtin_amdgcn_mfma_f32_16x16x32_bf16(af[i], bf[j], acc[i][j], 0, 0, 0);
        }
    }

#pragma unroll
    for (int j = 0; j < 4; j++) {
        const int n = n0 + wn * 64 + j * 16 + col;
        const float bias = bih[n] + bhh[n];
#pragma unroll
        for (int i = 0; i < 4; i++) {
            const int mb = m0 + wm * 64 + i * 16 + quad * 4;
#pragma unroll
            for (int r = 0; r < 4; r++)
                out[(size_t)(mb + r) * HDIM + n] = acc[i][j][r] + bias;
        }
    }
}

// ---------------------------------------------------------------------------
// Phase B: recurrence.  64 WGs x 512 thr = 8 groups (g = bid>>3, 8 batches)
// x 8 roles (role = bid&7, 128 neurons).  W_hh in registers.
//
// Sync v7 — tag-in-word, ONE MALL traversal per step:
//   hexch word = [bf16(h) << 16 | step-tag].  Producer release = ISSUE 4
//   tagged sc1 stores; no ack, no flag, no vmcnt on the release path.
//   Consumer wave w polls its 8-row x 2-col slice directly (8 x dwordx2);
//   a word is valid iff its tag == t.  Stale -> s_sleep 1, retry (poll IS
//   the data fetch — no separate detect+load RTTs).
//   Poll-queue hygiene (round-6 lesson): x_proj prefetch is issued post-
//   staging (retired under MFMA, ~2000 cy before next poll); out[] stores
//   are plain (L2-ack ~300 cy).  First poll vmcnt(0) therefore waits only
//   ~the h-store ack, which overlaps peer store visibility anyway.
//   Full join: bar1 makes each WG wait on all 8 producers every step, so
//   no producer can lap a slot (depth-2 safety as proven in round 5).
//   Fail-fast fuse: 1<<16 retries -> bounded-time absmax failure, no hang.
// ---------------------------------------------------------------------------
__global__ __launch_bounds__(512, 1)
void rnn_rec(float* __restrict__ out,          // in: x_proj (fp32); overwritten with h
             const float* __restrict__ Whh, const float* __restrict__ h0,
             unsigned* __restrict__ hexch)
{
    __shared__ short hlds[16 * 1032];   // rows 0..7 = batches, 8..15 = zeros

    const int tid  = threadIdx.x;
    const int g    = blockIdx.x >> 3;   // 0..7  (batches g*8 .. g*8+7)
    const int role = blockIdx.x & 7;    // 0..7  (neurons role*128 .. +127)
    const int lane = tid & 63;
    const int w    = tid >> 6;          // 0..7
    const int col  = lane & 15, quad = lane >> 4;
    const int nglob = role * 128 + w * 16 + col;
    const int b0   = quad * 4;          // C rows; batches valid only b0 < 8

    // zero MFMA batch rows 8..15 once (A rows 8..15 = 0 -> C rows 8..15 = 0)
    {
        unsigned* z = (unsigned*)(hlds + 8 * 1032);
        for (int i = tid; i < 4 * 1032; i += 512) z[i] = 0u;
    }

    // B-fragments: W_hh[n][k], k = kb*32 + quad*8 + j
    shortx8 bfrag[32];
    {
        const float* wrow = Whh + (size_t)nglob * HDIM + quad * 8;
#pragma unroll
        for (int kb = 0; kb < 32; kb++) {
            const floatx4* p = (const floatx4*)(wrow + kb * 32);
            bfrag[kb] = pack8(p[0], p[1]);
        }
    }
    __syncthreads();                    // zeros visible before first MFMA

    const int bsafe = b0 & 7;           // in-range batch index for (dummy) loads
    float xp[4], xpn[4];
#pragma unroll
    for (int r = 0; r < 4; r++)
        xp[r] = __builtin_nontemporal_load(
            out + (size_t)(g * 8 + bsafe + r) * (TDIM * HDIM) + nglob);

    const int cc = w * 128 + lane * 2;  // this lane's exchange columns (words)
    // slot stride 65536 words; group stride 8192 words (8 rows x 1024)
    const unsigned gbase = (unsigned)(g * 8192 + cc);

    for (int t = 0; t < TDIM; ++t) {
        // ================= staging =================
        if (t == 0) {
            const int c2 = tid * 2;     // 0..1022
#pragma unroll
            for (int j = 0; j < 8; j++) {
                floatx2 f = *(const floatx2*)(h0 + (size_t)(g * 8 + j) * HDIM + c2);
                const unsigned pk = (unsigned)(unsigned short)f2bf(f[0]) |
                                    ((unsigned)(unsigned short)f2bf(f[1]) << 16);
                *(unsigned*)(hlds + j * 1032 + c2) = pk;
            }
        } else {
            const unsigned long long msk = 0x0000FFFF0000FFFFULL;
            const unsigned long long tt  = (unsigned long long)(unsigned)t;
            const unsigned long long pat = tt | (tt << 32);
            const unsigned* base = hexch + ((unsigned)(t & 1) << 16) + gbase;
            unsigned long long hv[8];
            int guard = 0;
            for (;;) {
#pragma unroll
                for (int j = 0; j < 8; j++)
                    hv[j] = ld_mall8(base + (size_t)j * 1024);
                asm volatile("s_waitcnt vmcnt(0)" ::: "memory");
                __builtin_amdgcn_sched_barrier(0);
                bool bad = false;
#pragma unroll
                for (int j = 0; j < 8; j++)
                    bad |= ((hv[j] & msk) != pat);
                if (!__any((int)bad)) break;
                if (++guard > (1 << 16)) break;      // FAIL-FAST fuse
                asm volatile("s_sleep 1");
            }
            // extract bf16 values (high halves) -> LDS
#pragma unroll
            for (int j = 0; j < 8; j++) {
                const unsigned pk = (unsigned)((hv[j] >> 16) & 0xFFFFu) |
                                    (unsigned)((hv[j] >> 32) & 0xFFFF0000u);
                *(unsigned*)(hlds + j * 1032 + cc) = pk;
            }
        }

        // x_proj prefetch for t+1: issued HERE so it retires under MFMA and
        // is long gone from the VMEM queue by the next poll (round-6 lesson).
        if (t + 1 < TDIM) {
#pragma unroll
            for (int r = 0; r < 4; r++)
                xpn[r] = __builtin_nontemporal_load(
                    out + (size_t)(g * 8 + bsafe + r) * (TDIM * HDIM) + (size_t)(t + 1) * HDIM + nglob);
        }

        // bar1: all slices staged (LDS-only wait, no vmcnt drain)
        asm volatile("s_waitcnt lgkmcnt(0)" ::: "memory");
        __builtin_amdgcn_s_barrier();

        // ================= K loop: 32 MFMAs, 4 chains =================
        floatx4 a0 = (floatx4){0.f, 0.f, 0.f, 0.f};
        floatx4 a1 = a0, a2 = a0, a3 = a0;
#pragma unroll
        for (int kb = 0; kb < 32; kb += 4) {
            shortx8 f0 = *(const shortx8*)(hlds + col * 1032 + (kb + 0) * 32 + quad * 8);
            shortx8 f1 = *(const shortx8*)(hlds + col * 1032 + (kb + 1) * 32 + quad * 8);
            shortx8 f2 = *(const shortx8*)(hlds + col * 1032 + (kb + 2) * 32 + quad * 8);
            shortx8 f3 = *(const shortx8*)(hlds + col * 1032 + (kb + 3) * 32 + quad * 8);
            a0 = __builtin_amdgcn_mfma_f32_16x16x32_bf16(f0, bfrag[kb + 0], a0, 0, 0, 0);
            a1 = __builtin_amdgcn_mfma_f32_16x16x32_bf16(f1, bfrag[kb + 1], a1, 0, 0, 0);
            a2 = __builtin_amdgcn_mfma_f32_16x16x32_bf16(f2, bfrag[kb + 2], a2, 0, 0, 0);
            a3 = __builtin_amdgcn_mfma_f32_16x16x32_bf16(f3, bfrag[kb + 3], a3, 0, 0, 0);
        }
        floatx4 acc = (a0 + a1) + (a2 + a3);

        // ================= epilogue =================
        float hval[4];
#pragma unroll
        for (int r = 0; r < 4; r++)
            hval[r] = tanhf(xp[r] + acc[r]);

        // release = issue tagged h stores.  No ack, no flag, no wait.
        if (t + 1 < TDIM) {
            unsigned* hd = hexch + ((unsigned)((t + 1) & 1) << 16) + (unsigned)(g * 8192);
            const unsigned tag = (unsigned)(t + 1);
            if (b0 < 8) {
#pragma unroll
                for (int r = 0; r < 4; r++)
                    st_tag(hd + (size_t)(b0 + r) * 1024 + nglob,
                           ((unsigned)(unsigned short)f2bf(hval[r]) << 16) | tag);
            }
        }

        // WG-private out[] writes — plain stores (L2 ack), cheap under the
        // next poll's vmcnt(0)
        if (b0 < 8) {
#pragma unroll
            for (int r = 0; r < 4; r++) {
                const int b = g * 8 + b0 + r;
                const size_t oidx = (size_t)b * (TDIM * HDIM) + (size_t)t * HDIM + nglob;
                out[oidx] = hval[r];
                if (t == TDIM - 1)
                    out[(size_t)BSZ * TDIM * HDIM + (size_t)b * HDIM + nglob] = hval[r];
            }
        }
#pragma unroll
        for (int r = 0; r < 4; r++) xp[r] = xpn[r];

        // bar2: protect hlds from next staging (LDS-only wait)
        if (t + 1 < TDIM) {
            asm volatile("s_waitcnt lgkmcnt(0)" ::: "memory");
            __builtin_amdgcn_s_barrier();
        }
    }
}

// ---------------------------------------------------------------------------
extern "C" void kernel_launch(void* const* d_in, const int* in_sizes, int n_in,
                              void* d_out, int out_size, void* d_ws, size_t ws_size,
                              hipStream_t stream)
{
    const float* input = (const float*)d_in[0];
    const float* h0    = (const float*)d_in[1];
    const float* W_ih  = (const float*)d_in[2];
    const float* b_ih  = (const float*)d_in[3];
    const float* W_hh  = (const float*)d_in[4];
    const float* b_hh  = (const float*)d_in[5];
    float* out = (float*)d_out;

    unsigned* hexch = (unsigned*)d_ws;  // 2 slots x 8g x 8b x 1024 words = 512 KiB

    // stale tags from a previous run must not alias this run's (tag 0 unused)
    hipMemsetAsync(hexch, 0, (size_t)2 * 65536 * 4, stream);

    xp_gemm<<<dim3(4096), dim3(256), 0, stream>>>(input, W_ih, b_ih, b_hh, out);
    rnn_rec<<<dim3(64),   dim3(512), 0, stream>>>(out, W_hh, h0, hexch);
}